// Round 4
// baseline (698.296 us; speedup 1.0000x reference)
//
#include <hip/hip_runtime.h>
#include <hip/hip_bf16.h>
#include <math.h>

#define TOKENS 2048
#define IN_DIM 2048
#define VOCAB  32000

#define BM 256
#define BN 256
#define BK 64
#define NKSTEP (IN_DIM / BK)   // 32
#define NTILES ((TOKENS / BM) * (VOCAB / BN))  // 8*125 = 1000
#define NCT (VOCAB / BN)       // 125
#define PGRID 256              // persistent workgroups

typedef short s16x8 __attribute__((ext_vector_type(8)));
typedef float f32x4 __attribute__((ext_vector_type(4)));

// ---------- fp32 -> bf16 (round-to-nearest-even) ----------
__device__ __forceinline__ unsigned short f2bf_rne(float f) {
  unsigned int u = __float_as_uint(f);
  u += 0x7fffu + ((u >> 16) & 1u);
  return (unsigned short)(u >> 16);
}
__device__ __forceinline__ float bf2f(unsigned short h) {
  return __uint_as_float(((unsigned int)h) << 16);
}

__global__ __launch_bounds__(256) void convert_f32_to_bf16(
    const float* __restrict__ in, unsigned short* __restrict__ out, int n4) {
  int idx = blockIdx.x * blockDim.x + threadIdx.x;
  int stride = gridDim.x * blockDim.x;
  for (int i = idx; i < n4; i += stride) {
    float4 v = reinterpret_cast<const float4*>(in)[i];
    ushort4 o;
    o.x = f2bf_rne(v.x);
    o.y = f2bf_rne(v.y);
    o.z = f2bf_rne(v.z);
    o.w = f2bf_rne(v.w);
    reinterpret_cast<ushort4*>(out)[i] = o;
  }
}

// ---------- async global -> LDS, 16B per lane ----------
__device__ __forceinline__ void gload_lds16(const unsigned short* g, unsigned short* l) {
  __builtin_amdgcn_global_load_lds(
      (const __attribute__((address_space(1))) unsigned int*)g,
      (__attribute__((address_space(3))) unsigned int*)l, 16, 0, 0);
}

// ---------- persistent 256x256 8-phase GEMM + fused tile-softmax ----------
// 256 wgs; wg -> lid0 = (wg%8)*32 + wg/8 (XCD-chunked); tiles t = lid0 + 256*i.
// Flat K-step stream across tiles: during step s -> P0 stages Bh1(s+1),
// P2 stages A(s+2), P3 stages Bh0(s+2); one counted vmcnt(6) per step at P3.
// Tile-boundary KSTEPs take explicit next-tile source pointers.
// Epilogue: per-row tile max/sumexp -> partials; logits stored as
// bf16(l - M_tile) into the UPPER HALF of each row's own d_out slot.
__global__ __launch_bounds__(512, 2) void gemm_persist(
    const unsigned short* __restrict__ A,   // [TOKENS][IN_DIM] bf16
    const unsigned short* __restrict__ B,   // [VOCAB][IN_DIM] bf16
    unsigned short* __restrict__ CB,        // d_out as ushort; row r bf16 at 64000*r+32000
    float2* __restrict__ partials) {        // [TOKENS][NCT] (tile max, tile sumexp)
  __shared__ __align__(16) unsigned short lds[65536];  // 128 KiB staging
  __shared__ float scrM[1024];   // [256 rows][4 wc]
  __shared__ float scrS[1024];
  __shared__ float bcastM[256];

  const int tid = threadIdx.x;   // 0..511
  const int lane = tid & 63;
  const int wave = tid >> 6;     // 0..7
  const int wr = wave >> 2;      // 0..1  (M)
  const int wc = wave & 3;       // 0..3  (N)

  const int lid0 = (blockIdx.x & 7) * 32 + (blockIdx.x >> 3);
  const int ntile = (lid0 < NTILES - 3 * PGRID) ? 4 : 3;  // lid0<232 -> 4

  // staging geometry: half-tile = 128 rows x 64 cols; thread stages 2 chunks
  const int r0 = tid >> 3;
  const int c8 = (((tid & 7) ^ (r0 & 7)) << 3);
  const int ldsD0 = tid * 8;
  const int ldsD1 = (512 + tid) * 8;

  auto stA = [&](int buf, int h, const unsigned short* p0, const unsigned short* p1, int k) {
    size_t off = (size_t)h * (128 * IN_DIM) + k;
    int dst = buf * 32768 + h * 8192;
    gload_lds16(p0 + off, &lds[dst + ldsD0]);
    gload_lds16(p1 + off, &lds[dst + ldsD1]);
  };
  auto stB = [&](int buf, int h, const unsigned short* p0, const unsigned short* p1, int k) {
    size_t off = (size_t)h * (128 * IN_DIM) + k;
    int dst = 16384 + buf * 32768 + h * 8192;
    gload_lds16(p0 + off, &lds[dst + ldsD0]);
    gload_lds16(p1 + off, &lds[dst + ldsD1]);
  };

  // ds_read geometry (swizzle on read)
  const int sc0 = (((lane >> 4) ^ (lane & 7)) << 3);
  const int sc1 = (((4 + (lane >> 4)) ^ (lane & 7)) << 3);
  const int aRow = (wr * 128 + (lane & 15)) * 64;
  const int bRow = 16384 + (wc * 64 + (lane & 15)) * 64;

#define LDA(buf, m, kk) (*(const s16x8*)&lds[(buf) * 32768 + aRow + (m) * 1024 + ((kk) ? sc1 : sc0)])
#define LDB(buf, n, kk) (*(const s16x8*)&lds[(buf) * 32768 + bRow + (n) * 1024 + ((kk) ? sc1 : sc0)])

  f32x4 acc[8][4];

  // ---- tile-0 pointers
  int t = lid0;
  int curRow = (t & 7) * BM, curCol = (t >> 3) * BN;
  const unsigned short* cA0 = A + (size_t)(curRow + r0) * IN_DIM + c8;
  const unsigned short* cA1 = cA0 + (size_t)64 * IN_DIM;
  const unsigned short* cB0 = B + (size_t)(curCol + r0) * IN_DIM + c8;
  const unsigned short* cB1 = cB0 + (size_t)64 * IN_DIM;

  // ---- prologue: s0 full + s1 {A,Bh0}; vmcnt(6) retires s0
  stA(0, 0, cA0, cA1, 0);
  stA(0, 1, cA0, cA1, 0);
  stB(0, 0, cB0, cB1, 0);
  stB(0, 1, cB0, cB1, 0);
  stA(1, 0, cA0, cA1, 64);
  stA(1, 1, cA0, cA1, 64);
  stB(1, 0, cB0, cB1, 64);
  asm volatile("s_waitcnt vmcnt(6)" ::: "memory");
  __builtin_amdgcn_s_barrier();

#define KSTEP(bufc, kn1, kn2, PB1A, PB1B, PA2A, PA2B, PB2A, PB2B)                   \
  {                                                                                 \
    s16x8 aL[4][2], aH[4][2], bL[2][2], bH[2][2];                                   \
    /* P0: 12 reads; stage Bh1(s+1) -> buf^1 */                                     \
    _Pragma("unroll") for (int m = 0; m < 4; ++m) {                                 \
      aL[m][0] = LDA(bufc, m, 0);                                                   \
      aL[m][1] = LDA(bufc, m, 1);                                                   \
    }                                                                               \
    _Pragma("unroll") for (int n = 0; n < 2; ++n) {                                 \
      bL[n][0] = LDB(bufc, n, 0);                                                   \
      bL[n][1] = LDB(bufc, n, 1);                                                   \
    }                                                                               \
    stB((bufc) ^ 1, 1, PB1A, PB1B, kn1);                                            \
    asm volatile("s_waitcnt lgkmcnt(8)" ::: "memory");                              \
    __builtin_amdgcn_s_barrier();                                                   \
    asm volatile("s_waitcnt lgkmcnt(0)" ::: "memory");                              \
    __builtin_amdgcn_s_setprio(1);                                                  \
    _Pragma("unroll") for (int m = 0; m < 4; ++m)                                   \
        _Pragma("unroll") for (int n = 0; n < 2; ++n) {                             \
      acc[m][n] = __builtin_amdgcn_mfma_f32_16x16x32_bf16(aL[m][0], bL[n][0], acc[m][n], 0, 0, 0); \
      acc[m][n] = __builtin_amdgcn_mfma_f32_16x16x32_bf16(aL[m][1], bL[n][1], acc[m][n], 0, 0, 0); \
    }                                                                               \
    __builtin_amdgcn_s_setprio(0);                                                  \
    __builtin_amdgcn_s_barrier();                                                   \
    /* P1: 8 reads aH */                                                            \
    _Pragma("unroll") for (int m = 0; m < 4; ++m) {                                 \
      aH[m][0] = LDA(bufc, 4 + m, 0);                                               \
      aH[m][1] = LDA(bufc, 4 + m, 1);                                               \
    }                                                                               \
    __builtin_amdgcn_s_barrier();                                                   \
    asm volatile("s_waitcnt lgkmcnt(0)" ::: "memory");                              \
    __builtin_amdgcn_s_setprio(1);                                                  \
    _Pragma("unroll") for (int m = 0; m < 4; ++m)                                   \
        _Pragma("unroll") for (int n = 0; n < 2; ++n) {                             \
      acc[4 + m][n] = __builtin_amdgcn_mfma_f32_16x16x32_bf16(aH[m][0], bL[n][0], acc[4 + m][n], 0, 0, 0); \
      acc[4 + m][n] = __builtin_amdgcn_mfma_f32_16x16x32_bf16(aH[m][1], bL[n][1], acc[4 + m][n], 0, 0, 0); \
    }                                                                               \
    __builtin_amdgcn_s_setprio(0);                                                  \
    __builtin_amdgcn_s_barrier();                                                   \
    /* P2: 4 reads bH; stage A(s+2) h0,h1 -> bufc (A slots dead after P1 bar) */    \
    _Pragma("unroll") for (int n = 0; n < 2; ++n) {                                 \
      bH[n][0] = LDB(bufc, 2 + n, 0);                                               \
      bH[n][1] = LDB(bufc, 2 + n, 1);                                               \
    }                                                                               \
    stA((bufc), 0, PA2A, PA2B, kn2);                                                \
    stA((bufc), 1, PA2A, PA2B, kn2);                                                \
    __builtin_amdgcn_s_barrier();                                                   \
    asm volatile("s_waitcnt lgkmcnt(0)" ::: "memory");                              \
    __builtin_amdgcn_s_setprio(1);                                                  \
    _Pragma("unroll") for (int m = 0; m < 4; ++m)                                   \
        _Pragma("unroll") for (int n = 0; n < 2; ++n) {                             \
      acc[4 + m][2 + n] = __builtin_amdgcn_mfma_f32_16x16x32_bf16(aH[m][0], bH[n][0], acc[4 + m][2 + n], 0, 0, 0); \
      acc[4 + m][2 + n] = __builtin_amdgcn_mfma_f32_16x16x32_bf16(aH[m][1], bH[n][1], acc[4 + m][2 + n], 0, 0, 0); \
    }                                                                               \
    __builtin_amdgcn_s_setprio(0);                                                  \
    __builtin_amdgcn_s_barrier();                                                   \
    /* P3: stage Bh0(s+2) -> bufc (dead after P2 bar); reg-only MFMA; vmcnt(6) */   \
    stB((bufc), 0, PB2A, PB2B, kn2);                                                \
    __builtin_amdgcn_s_setprio(1);                                                  \
    _Pragma("unroll") for (int m = 0; m < 4; ++m)                                   \
        _Pragma("unroll") for (int n = 0; n < 2; ++n) {                             \
      acc[m][2 + n] = __builtin_amdgcn_mfma_f32_16x16x32_bf16(aL[m][0], bH[n][0], acc[m][2 + n], 0, 0, 0); \
      acc[m][2 + n] = __builtin_amdgcn_mfma_f32_16x16x32_bf16(aL[m][1], bH[n][1], acc[m][2 + n], 0, 0, 0); \
    }                                                                               \
    __builtin_amdgcn_s_setprio(0);                                                  \
    asm volatile("s_waitcnt vmcnt(6)" ::: "memory");                                \
    __builtin_amdgcn_s_barrier();                                                   \
  }

  for (int ti = 0; ti < ntile; ++ti) {
    const int curColTile = curCol / BN;
    // next tile (clamped to current on the last iteration -> harmless reload)
    const int tn = (ti + 1 < ntile) ? t + PGRID : t;
    const int nRow = (tn & 7) * BM, nCol = (tn >> 3) * BN;
    const unsigned short* nA0 = A + (size_t)(nRow + r0) * IN_DIM + c8;
    const unsigned short* nA1 = nA0 + (size_t)64 * IN_DIM;
    const unsigned short* nB0 = B + (size_t)(nCol + r0) * IN_DIM + c8;
    const unsigned short* nB1 = nB0 + (size_t)64 * IN_DIM;

#pragma unroll
    for (int m = 0; m < 8; ++m)
#pragma unroll
      for (int n = 0; n < 4; ++n) acc[m][n] = (f32x4){0.f, 0.f, 0.f, 0.f};

    for (int i = 0; i < 15; ++i) {
      const int k = i * 128;
      KSTEP(0, k + 64, k + 128, cB0, cB1, cA0, cA1, cB0, cB1);
      KSTEP(1, k + 128, k + 192, cB0, cB1, cA0, cA1, cB0, cB1);
    }
    // boundary pair: steps 30,31 prefetch next tile's steps 0,1
    KSTEP(0, 1984, 0, cB0, cB1, nA0, nA1, nB0, nB1);
    KSTEP(1, 0, 64, nB0, nB1, nA0, nA1, nB0, nB1);

    // ---- epilogue (no staging-LDS use; overlaps in-flight prefetch) ----
    // (1) per-wave 64-col (mx, sumexp) per row
#pragma unroll
    for (int m = 0; m < 8; ++m) {
#pragma unroll
      for (int jj = 0; jj < 4; ++jj) {
        float v0 = acc[m][0][jj], v1 = acc[m][1][jj], v2 = acc[m][2][jj], v3 = acc[m][3][jj];
        float mx = fmaxf(fmaxf(v0, v1), fmaxf(v2, v3));
#pragma unroll
        for (int off = 1; off < 16; off <<= 1) mx = fmaxf(mx, __shfl_xor(mx, off));
        float s = __expf(v0 - mx) + __expf(v1 - mx) + __expf(v2 - mx) + __expf(v3 - mx);
#pragma unroll
        for (int off = 1; off < 16; off <<= 1) s += __shfl_xor(s, off);
        if ((lane & 15) == 0) {
          int r = wr * 128 + m * 16 + ((lane >> 4) << 2) + jj;
          scrM[r * 4 + wc] = mx;
          scrS[r * 4 + wc] = s;
        }
      }
    }
    __syncthreads();
    // (2) cross-wave 256-col reduce -> partials + broadcast M
    if (tid < 256) {
      float m0 = scrM[tid * 4 + 0], m1 = scrM[tid * 4 + 1];
      float m2 = scrM[tid * 4 + 2], m3 = scrM[tid * 4 + 3];
      float M = fmaxf(fmaxf(m0, m1), fmaxf(m2, m3));
      float S = scrS[tid * 4 + 0] * __expf(m0 - M) + scrS[tid * 4 + 1] * __expf(m1 - M) +
                scrS[tid * 4 + 2] * __expf(m2 - M) + scrS[tid * 4 + 3] * __expf(m3 - M);
      partials[(size_t)(curRow + tid) * NCT + curColTile] = make_float2(M, S);
      bcastM[tid] = M;
    }
    __syncthreads();
    // (3) store bf16(logit - M_tile) into upper half of each row's d_out slot
#pragma unroll
    for (int m = 0; m < 8; ++m) {
#pragma unroll
      for (int jj = 0; jj < 4; ++jj) {
        int rloc = wr * 128 + m * 16 + ((lane >> 4) << 2) + jj;
        float M = bcastM[rloc];
        unsigned short* cp = CB + (size_t)64000 * (curRow + rloc) + 32000 +
                             curCol + wc * 64 + (lane & 15);
#pragma unroll
        for (int n = 0; n < 4; ++n) cp[n * 16] = f2bf_rne(acc[m][n][jj] - M);
      }
    }
    // advance tile (scr arrays re-synced by the 32 K-steps' barriers)
    t = tn;
    curRow = nRow;
    curCol = nCol;
    cA0 = nA0;
    cA1 = nA1;
    cB0 = nB0;
    cB1 = nB1;
  }
#undef LDA
#undef LDB
#undef KSTEP
}

// ---------- combine per-tile partials -> per-row (max, 1/sum) ----------
__global__ __launch_bounds__(256) void reduce_stats(
    const float2* __restrict__ partials, float2* __restrict__ stats) {
  int row = blockIdx.x * blockDim.x + threadIdx.x;
  if (row >= TOKENS) return;
  const float2* p = partials + (size_t)row * NCT;
  float M = -3.4e38f, S = 0.f;
  for (int i = 0; i < NCT; ++i) {
    float2 v = p[i];
    if (v.x > M) {
      S *= __expf(M - v.x);
      M = v.x;
    }
    S += v.y * __expf(v.x - M);
  }
  stats[row] = make_float2(M, 1.f / S);
}

// ---------- apply: bf16 rel-logits (upper half of own slot) -> fp32 probs ----------
__global__ __launch_bounds__(256) void apply_softmax(
    float* __restrict__ Out, const float2* __restrict__ partials,
    const float2* __restrict__ stats) {
  __shared__ __align__(16) unsigned short xrow[VOCAB];  // 64 KB
  const int row = blockIdx.x;
  const unsigned short* src = (const unsigned short*)Out + (size_t)64000 * row + 32000;
  for (int c = threadIdx.x; c < VOCAB / 8; c += 256)
    reinterpret_cast<s16x8*>(xrow)[c] = reinterpret_cast<const s16x8*>(src)[c];
  __syncthreads();
  const float2 st = stats[row];
  const float M = st.x, invS = st.y;
  const float2* pr = partials + (size_t)row * NCT;
  float4* dst = reinterpret_cast<float4*>(Out + (size_t)row * VOCAB);
  for (int c = threadIdx.x; c < VOCAB / 8; c += 256) {
    s16x8 xv = reinterpret_cast<const s16x8*>(xrow)[c];
    float base = pr[c >> 5].x - M;  // 256-col group = (8c)>>8
    float4 o0, o1;
    o0.x = __expf(bf2f((unsigned short)xv[0]) + base) * invS;
    o0.y = __expf(bf2f((unsigned short)xv[1]) + base) * invS;
    o0.z = __expf(bf2f((unsigned short)xv[2]) + base) * invS;
    o0.w = __expf(bf2f((unsigned short)xv[3]) + base) * invS;
    o1.x = __expf(bf2f((unsigned short)xv[4]) + base) * invS;
    o1.y = __expf(bf2f((unsigned short)xv[5]) + base) * invS;
    o1.z = __expf(bf2f((unsigned short)xv[6]) + base) * invS;
    o1.w = __expf(bf2f((unsigned short)xv[7]) + base) * invS;
    dst[c * 2] = o0;
    dst[c * 2 + 1] = o1;
  }
}

extern "C" void kernel_launch(void* const* d_in, const int* in_sizes, int n_in,
                              void* d_out, int out_size, void* d_ws, size_t ws_size,
                              hipStream_t stream) {
  const float* x = (const float*)d_in[0];
  // d_in[1] = target (int64), unused by the reference forward
  const float* w = (const float*)d_in[2];
  float* out = (float*)d_out;

  // ws layout: xbf 8MB | wbf 131MB | partials 2.05MB | stats 16KB (~141.2MB)
  unsigned short* xbf = (unsigned short*)d_ws;
  unsigned short* wbf = xbf + (size_t)TOKENS * IN_DIM;
  float2* partials = (float2*)(wbf + (size_t)VOCAB * IN_DIM);
  float2* stats = partials + (size_t)TOKENS * NCT;

  convert_f32_to_bf16<<<512, 256, 0, stream>>>(x, xbf, TOKENS * IN_DIM / 4);
  convert_f32_to_bf16<<<2048, 256, 0, stream>>>(w, wbf, VOCAB * IN_DIM / 4);
  gemm_persist<<<PGRID, 512, 0, stream>>>(xbf, wbf, (unsigned short*)d_out, partials);
  reduce_stats<<<TOKENS / 256, 256, 0, stream>>>(partials, stats);
  apply_softmax<<<TOKENS, 256, 0, stream>>>(out, partials, stats);
}

// Round 6
// 484.465 us; speedup vs baseline: 1.4414x; 1.4414x over previous
//
#include <hip/hip_runtime.h>
#include <hip/hip_bf16.h>
#include <math.h>

#define TOKENS 2048
#define IN_DIM 2048
#define VOCAB  32000

#define BM 256
#define BN 256
#define BK 64
#define NKSTEP (IN_DIM / BK)                     // 32
#define GEMM_GRID ((TOKENS / BM) * (VOCAB / BN)) // 8 * 125 = 1000
#define NCT (VOCAB / BN)                         // 125 col tiles

typedef short s16x8 __attribute__((ext_vector_type(8)));
typedef float f32x4 __attribute__((ext_vector_type(4)));

// ---------- fp32 -> bf16 (round-to-nearest-even) ----------
__device__ __forceinline__ unsigned short f2bf_rne(float f) {
  unsigned int u = __float_as_uint(f);
  u += 0x7fffu + ((u >> 16) & 1u);
  return (unsigned short)(u >> 16);
}
__device__ __forceinline__ float bf2f(unsigned short h) {
  return __uint_as_float(((unsigned int)h) << 16);
}

__global__ __launch_bounds__(256) void convert_f32_to_bf16(
    const float* __restrict__ in, unsigned short* __restrict__ out, int n4) {
  int idx = blockIdx.x * blockDim.x + threadIdx.x;
  int stride = gridDim.x * blockDim.x;
  for (int i = idx; i < n4; i += stride) {
    float4 v = reinterpret_cast<const float4*>(in)[i];
    ushort4 o;
    o.x = f2bf_rne(v.x);
    o.y = f2bf_rne(v.y);
    o.z = f2bf_rne(v.z);
    o.w = f2bf_rne(v.w);
    reinterpret_cast<ushort4*>(out)[i] = o;
  }
}

// ---------- async global -> LDS, 16B per lane ----------
__device__ __forceinline__ void gload_lds16(const unsigned short* g, unsigned short* l) {
  __builtin_amdgcn_global_load_lds(
      (const __attribute__((address_space(1))) unsigned int*)g,
      (__attribute__((address_space(3))) unsigned int*)l, 16, 0, 0);
}

// ---------- 256x256 8-phase GEMM + fused per-tile softmax partials ----------
// Round-3 K-loop (known good). Epilogue: per-row tile (max,sumexp) -> partials,
// then bf16(logit - M_tile) stored PAIR-LOCALLY packed:
//   lane pair (e,e+1) holds pk(e,n) = cols {16n+e, 16n+e+1} for n=0..3;
//   inst0: lane stores p[lane&1]   at ushort off 16*(lane&1) + e   (cols  0..31)
//   inst1: lane stores p[2+lane&1] at ushort off 32+16*(lane&1)+e  (cols 32..63)
// -> 64B contiguous per 16-lane group per instruction; no cross-pair shuffles.
__global__ __launch_bounds__(512, 2) void gemm_bt(
    const unsigned short* __restrict__ A,   // [TOKENS][IN_DIM] bf16
    const unsigned short* __restrict__ B,   // [VOCAB][IN_DIM] bf16
    unsigned short* __restrict__ CB,        // d_out as ushort; row r bf16 at 64000*r+32000
    float2* __restrict__ partials) {        // [TOKENS][NCT] (tile max, tile sumexp)
  __shared__ __align__(16) unsigned short lds[65536];  // 128 KiB

  const int tid = threadIdx.x;   // 0..511
  const int lane = tid & 63;
  const int wave = tid >> 6;     // 0..7
  const int wr = wave >> 2;      // 0..1  (M)
  const int wc = wave & 3;       // 0..3  (N)

  const int bid = blockIdx.x;
  const int lid = (bid & 7) * (GEMM_GRID / 8) + (bid >> 3);
  const int rowTile = lid & 7;
  const int colTile = lid >> 3;
  const int rowBase = rowTile * BM;
  const int colBase = colTile * BN;

  // staging geometry: half-tile = 128 rows x 64 cols = 1024 chunks of 16B
  const int r0 = tid >> 3;
  const int r1 = 64 + r0;
  const int c8 = (((tid & 7) ^ (r0 & 7)) << 3);
  const unsigned short* srcA0 = A + (size_t)(rowBase + r0) * IN_DIM + c8;
  const unsigned short* srcA1 = A + (size_t)(rowBase + r1) * IN_DIM + c8;
  const unsigned short* srcB0 = B + (size_t)(colBase + r0) * IN_DIM + c8;
  const unsigned short* srcB1 = B + (size_t)(colBase + r1) * IN_DIM + c8;
  const int ldsD0 = tid * 8;
  const int ldsD1 = (512 + tid) * 8;

  auto stageA = [&](int buf, int h, int k) {
    size_t off = (size_t)h * (128 * IN_DIM) + k;
    int dst = buf * 32768 + h * 8192;
    gload_lds16(srcA0 + off, &lds[dst + ldsD0]);
    gload_lds16(srcA1 + off, &lds[dst + ldsD1]);
  };
  auto stageB = [&](int buf, int h, int k) {
    size_t off = (size_t)h * (128 * IN_DIM) + k;
    int dst = 16384 + buf * 32768 + h * 8192;
    gload_lds16(srcB0 + off, &lds[dst + ldsD0]);
    gload_lds16(srcB1 + off, &lds[dst + ldsD1]);
  };

  const int sc0 = (((lane >> 4) ^ (lane & 7)) << 3);
  const int sc1 = (((4 + (lane >> 4)) ^ (lane & 7)) << 3);
  const int aRow = (wr * 128 + (lane & 15)) * 64;
  const int bRow = 16384 + (wc * 64 + (lane & 15)) * 64;

#define LDA(buf, m, kk) (*(const s16x8*)&lds[(buf) * 32768 + aRow + (m) * 1024 + ((kk) ? sc1 : sc0)])
#define LDB(buf, n, kk) (*(const s16x8*)&lds[(buf) * 32768 + bRow + (n) * 1024 + ((kk) ? sc1 : sc0)])

  f32x4 acc[8][4] = {};

  // ---- prologue: step0 (8) + A(1) (4) + Bh0(1) (2); vmcnt(6) retires step0
  stageA(0, 0, 0);
  stageA(0, 1, 0);
  stageB(0, 0, 0);
  stageB(0, 1, 0);
  stageA(1, 0, 64);
  stageA(1, 1, 64);
  stageB(1, 0, 64);
  asm volatile("s_waitcnt vmcnt(6)" ::: "memory");
  __builtin_amdgcn_s_barrier();

#define KSTEP(bufc, kn1, kn2)                                                       \
  {                                                                                 \
    s16x8 aL[4][2], aH[4][2], bL[2][2], bH[2][2];                                   \
    /* P0: 12 reads; stage B h1(t+1) -> buf^1 @kn1 */                               \
    _Pragma("unroll") for (int m = 0; m < 4; ++m) {                                 \
      aL[m][0] = LDA(bufc, m, 0);                                                   \
      aL[m][1] = LDA(bufc, m, 1);                                                   \
    }                                                                               \
    _Pragma("unroll") for (int n = 0; n < 2; ++n) {                                 \
      bL[n][0] = LDB(bufc, n, 0);                                                   \
      bL[n][1] = LDB(bufc, n, 1);                                                   \
    }                                                                               \
    stageB((bufc) ^ 1, 1, kn1);                                                     \
    asm volatile("s_waitcnt lgkmcnt(8)" ::: "memory");                              \
    __builtin_amdgcn_s_barrier();                                                   \
    asm volatile("s_waitcnt lgkmcnt(0)" ::: "memory");                              \
    __builtin_amdgcn_s_setprio(1);                                                  \
    _Pragma("unroll") for (int m = 0; m < 4; ++m)                                   \
        _Pragma("unroll") for (int n = 0; n < 2; ++n) {                             \
      acc[m][n] = __builtin_amdgcn_mfma_f32_16x16x32_bf16(aL[m][0], bL[n][0], acc[m][n], 0, 0, 0); \
      acc[m][n] = __builtin_amdgcn_mfma_f32_16x16x32_bf16(aL[m][1], bL[n][1], acc[m][n], 0, 0, 0); \
    }                                                                               \
    __builtin_amdgcn_s_setprio(0);                                                  \
    __builtin_amdgcn_s_barrier();                                                   \
    /* P1: 8 reads aH; no stage */                                                  \
    _Pragma("unroll") for (int m = 0; m < 4; ++m) {                                 \
      aH[m][0] = LDA(bufc, 4 + m, 0);                                               \
      aH[m][1] = LDA(bufc, 4 + m, 1);                                               \
    }                                                                               \
    __builtin_amdgcn_s_barrier();                                                   \
    asm volatile("s_waitcnt lgkmcnt(0)" ::: "memory");                              \
    __builtin_amdgcn_s_setprio(1);                                                  \
    _Pragma("unroll") for (int m = 0; m < 4; ++m)                                   \
        _Pragma("unroll") for (int n = 0; n < 2; ++n) {                             \
      acc[4 + m][n] = __builtin_amdgcn_mfma_f32_16x16x32_bf16(aH[m][0], bL[n][0], acc[4 + m][n], 0, 0, 0); \
      acc[4 + m][n] = __builtin_amdgcn_mfma_f32_16x16x32_bf16(aH[m][1], bL[n][1], acc[4 + m][n], 0, 0, 0); \
    }                                                                               \
    __builtin_amdgcn_s_setprio(0);                                                  \
    __builtin_amdgcn_s_barrier();                                                   \
    /* P2: 4 reads bH; stage A h0,h1(t+2) -> bufc @kn2 (A slots dead since P1 bar) */ \
    _Pragma("unroll") for (int n = 0; n < 2; ++n) {                                 \
      bH[n][0] = LDB(bufc, 2 + n, 0);                                               \
      bH[n][1] = LDB(bufc, 2 + n, 1);                                               \
    }                                                                               \
    stageA((bufc), 0, kn2);                                                         \
    stageA((bufc), 1, kn2);                                                         \
    __builtin_amdgcn_s_barrier();                                                   \
    asm volatile("s_waitcnt lgkmcnt(0)" ::: "memory");                              \
    __builtin_amdgcn_s_setprio(1);                                                  \
    _Pragma("unroll") for (int m = 0; m < 4; ++m)                                   \
        _Pragma("unroll") for (int n = 0; n < 2; ++n) {                             \
      acc[4 + m][2 + n] = __builtin_amdgcn_mfma_f32_16x16x32_bf16(aH[m][0], bH[n][0], acc[4 + m][2 + n], 0, 0, 0); \
      acc[4 + m][2 + n] = __builtin_amdgcn_mfma_f32_16x16x32_bf16(aH[m][1], bH[n][1], acc[4 + m][2 + n], 0, 0, 0); \
    }                                                                               \
    __builtin_amdgcn_s_setprio(0);                                                  \
    __builtin_amdgcn_s_barrier();                                                   \
    /* P3: stage B h0(t+2) -> bufc @kn2 (dead since P2 bar); reg-only MFMA; */      \
    /* counted vmcnt(6) AFTER MFMA retires B h1(t+1) -> buf^1 fully resident */     \
    stageB((bufc), 0, kn2);                                                         \
    __builtin_amdgcn_s_setprio(1);                                                  \
    _Pragma("unroll") for (int m = 0; m < 4; ++m)                                   \
        _Pragma("unroll") for (int n = 0; n < 2; ++n) {                             \
      acc[m][2 + n] = __builtin_amdgcn_mfma_f32_16x16x32_bf16(aL[m][0], bH[n][0], acc[m][2 + n], 0, 0, 0); \
      acc[m][2 + n] = __builtin_amdgcn_mfma_f32_16x16x32_bf16(aL[m][1], bH[n][1], acc[m][2 + n], 0, 0, 0); \
    }                                                                               \
    __builtin_amdgcn_s_setprio(0);                                                  \
    asm volatile("s_waitcnt vmcnt(6)" ::: "memory");                                \
    __builtin_amdgcn_s_barrier();                                                   \
  }

  for (int i = 0; i < NKSTEP / 2; ++i) {
    const int k = i * 128;
    KSTEP(0, (k + 64) & (IN_DIM - 1), (k + 128) & (IN_DIM - 1));
    KSTEP(1, (k + 128) & (IN_DIM - 1), (k + 192) & (IN_DIM - 1));
  }

  // drain wrapped prefetches before LDS reuse
  asm volatile("s_waitcnt vmcnt(0)" ::: "memory");
  __syncthreads();

  // ---- (1) per-row tile stats: wave-level 64-col (max, sumexp) ----
  float* lmax = reinterpret_cast<float*>(lds);   // [256][4]
  float* lsum = lmax + 1024;                     // [256][4]
  float* bM = lmax + 2048;                       // [256] broadcast tile max
#pragma unroll
  for (int m = 0; m < 8; ++m) {
#pragma unroll
    for (int jj = 0; jj < 4; ++jj) {
      float v0 = acc[m][0][jj], v1 = acc[m][1][jj], v2 = acc[m][2][jj], v3 = acc[m][3][jj];
      float mx = fmaxf(fmaxf(v0, v1), fmaxf(v2, v3));
#pragma unroll
      for (int off = 1; off < 16; off <<= 1) mx = fmaxf(mx, __shfl_xor(mx, off));
      float s = __expf(v0 - mx) + __expf(v1 - mx) + __expf(v2 - mx) + __expf(v3 - mx);
#pragma unroll
      for (int off = 1; off < 16; off <<= 1) s += __shfl_xor(s, off);
      if ((lane & 15) == 0) {
        int r = wr * 128 + m * 16 + ((lane >> 4) << 2) + jj;
        lmax[r * 4 + wc] = mx;
        lsum[r * 4 + wc] = s;
      }
    }
  }
  __syncthreads();
  // ---- (2) cross-wave 256-col reduce -> partials + broadcast M ----
  if (tid < 256) {
    float m0 = lmax[tid * 4 + 0], m1 = lmax[tid * 4 + 1];
    float m2 = lmax[tid * 4 + 2], m3 = lmax[tid * 4 + 3];
    float M = fmaxf(fmaxf(m0, m1), fmaxf(m2, m3));
    float S = lsum[tid * 4 + 0] * __expf(m0 - M) + lsum[tid * 4 + 1] * __expf(m1 - M) +
              lsum[tid * 4 + 2] * __expf(m2 - M) + lsum[tid * 4 + 3] * __expf(m3 - M);
    partials[(size_t)(rowBase + tid) * NCT + colTile] = make_float2(M, S);
    bM[tid] = M;
  }
  __syncthreads();

  // ---- (3) pair-local packed bf16(logit - M_tile) stores ----
  const int par = lane & 1;
  const int e = (lane & 15) & ~1;  // pair base col within 16
#pragma unroll
  for (int m = 0; m < 8; ++m) {
#pragma unroll
    for (int jj = 0; jj < 4; ++jj) {
      int rloc = wr * 128 + m * 16 + ((lane >> 4) << 2) + jj;
      float M = bM[rloc];
      unsigned int p[4];
#pragma unroll
      for (int n = 0; n < 4; ++n) {
        float v = acc[m][n][jj] - M;
        float u = __shfl_xor(v, 1);
        float lo = par ? u : v;   // col e value
        float hi = par ? v : u;   // col e+1 value
        unsigned int pk;
        asm("v_cvt_pk_bf16_f32 %0, %1, %2" : "=v"(pk) : "v"(lo), "v"(hi));
        p[n] = pk;  // pk(e, n) — identical in both lanes of the pair
      }
      unsigned int q0 = par ? p[1] : p[0];
      unsigned int q1 = par ? p[3] : p[2];
      unsigned short* base = CB + (size_t)64000 * (rowBase + rloc) + 32000 +
                             colBase + wc * 64;
      *reinterpret_cast<unsigned int*>(base + 16 * par + e) = q0;       // cols  0..31
      *reinterpret_cast<unsigned int*>(base + 32 + 16 * par + e) = q1;  // cols 32..63
    }
  }
#undef LDA
#undef LDB
#undef KSTEP
}

// ---------- combine per-tile partials -> per-row (max, 1/sum) ----------
__global__ __launch_bounds__(256) void reduce_stats(
    const float2* __restrict__ partials, float2* __restrict__ stats) {
  int row = blockIdx.x * blockDim.x + threadIdx.x;
  if (row >= TOKENS) return;
  const float2* p = partials + (size_t)row * NCT;
  float M = -3.4e38f, S = 0.f;
  for (int i = 0; i < NCT; ++i) {
    float2 v = p[i];
    if (v.x > M) {
      S *= __expf(M - v.x);
      M = v.x;
    }
    S += v.y * __expf(v.x - M);
  }
  stats[row] = make_float2(M, 1.f / S);
}

// ---------- apply: bf16 rel-logits (upper half of own slot) -> fp32 probs ----------
__global__ __launch_bounds__(256) void apply_softmax(
    float* __restrict__ Out, const float2* __restrict__ partials,
    const float2* __restrict__ stats) {
  __shared__ __align__(16) unsigned short xrow[VOCAB];  // 64 KB -> 2 blocks/CU
  const int row = blockIdx.x;
  const unsigned short* src = (const unsigned short*)Out + (size_t)64000 * row + 32000;
  for (int c = threadIdx.x; c < VOCAB / 8; c += 256)
    reinterpret_cast<s16x8*>(xrow)[c] = reinterpret_cast<const s16x8*>(src)[c];
  __syncthreads();
  const float2 st = stats[row];
  const float M = st.x, invS = st.y;
  const float2* pr = partials + (size_t)row * NCT;
  float4* dst = reinterpret_cast<float4*>(Out + (size_t)row * VOCAB);
  for (int c = threadIdx.x; c < VOCAB / 8; c += 256) {
    s16x8 xv = reinterpret_cast<const s16x8*>(xrow)[c];
    float base = pr[c >> 5].x - M;  // 256-col tile group
    float4 o0, o1;
    o0.x = __expf(bf2f((unsigned short)xv[0]) + base) * invS;
    o0.y = __expf(bf2f((unsigned short)xv[1]) + base) * invS;
    o0.z = __expf(bf2f((unsigned short)xv[2]) + base) * invS;
    o0.w = __expf(bf2f((unsigned short)xv[3]) + base) * invS;
    o1.x = __expf(bf2f((unsigned short)xv[4]) + base) * invS;
    o1.y = __expf(bf2f((unsigned short)xv[5]) + base) * invS;
    o1.z = __expf(bf2f((unsigned short)xv[6]) + base) * invS;
    o1.w = __expf(bf2f((unsigned short)xv[7]) + base) * invS;
    dst[c * 2] = o0;
    dst[c * 2 + 1] = o1;
  }
}

extern "C" void kernel_launch(void* const* d_in, const int* in_sizes, int n_in,
                              void* d_out, int out_size, void* d_ws, size_t ws_size,
                              hipStream_t stream) {
  const float* x = (const float*)d_in[0];
  // d_in[1] = target (int64), unused by the reference forward
  const float* w = (const float*)d_in[2];
  float* out = (float*)d_out;

  // ws layout: xbf 8MB | wbf 131MB | partials 2.05MB | stats 16KB (~141.2MB)
  unsigned short* xbf = (unsigned short*)d_ws;
  unsigned short* wbf = xbf + (size_t)TOKENS * IN_DIM;
  float2* partials = (float2*)(wbf + (size_t)VOCAB * IN_DIM);
  float2* stats = partials + (size_t)TOKENS * NCT;

  convert_f32_to_bf16<<<512, 256, 0, stream>>>(x, xbf, TOKENS * IN_DIM / 4);
  convert_f32_to_bf16<<<2048, 256, 0, stream>>>(w, wbf, VOCAB * IN_DIM / 4);
  gemm_bt<<<GEMM_GRID, 512, 0, stream>>>(xbf, wbf, (unsigned short*)d_out, partials);
  reduce_stats<<<TOKENS / 256, 256, 0, stream>>>(partials, stats);
  apply_softmax<<<TOKENS, 256, 0, stream>>>(out, partials, stats);
}

// Round 7
// 467.707 us; speedup vs baseline: 1.4930x; 1.0358x over previous
//
#include <hip/hip_runtime.h>
#include <hip/hip_bf16.h>
#include <math.h>

#define TOKENS 2048
#define IN_DIM 2048
#define VOCAB  32000

#define BM 256
#define BN 256
#define BK 64
#define NKSTEP (IN_DIM / BK)                     // 32
#define GEMM_GRID ((TOKENS / BM) * (VOCAB / BN)) // 8 * 125 = 1000
#define NCT (VOCAB / BN)                         // 125 col tiles

typedef short s16x8 __attribute__((ext_vector_type(8)));
typedef float f32x4 __attribute__((ext_vector_type(4)));

// ---------- fp32 -> bf16 (round-to-nearest-even) ----------
__device__ __forceinline__ unsigned short f2bf_rne(float f) {
  unsigned int u = __float_as_uint(f);
  u += 0x7fffu + ((u >> 16) & 1u);
  return (unsigned short)(u >> 16);
}
__device__ __forceinline__ float bf2f(unsigned short h) {
  return __uint_as_float(((unsigned int)h) << 16);
}

// ---------- fused convert: X then W, one grid-stride launch ----------
__global__ __launch_bounds__(256) void convert_all(
    const float* __restrict__ x, const float* __restrict__ w,
    unsigned short* __restrict__ xbf, unsigned short* __restrict__ wbf) {
  const int NX = TOKENS * IN_DIM / 4;   // 1,048,576 float4
  const int NW = VOCAB * IN_DIM / 4;    // 16,384,000 float4
  int idx = blockIdx.x * blockDim.x + threadIdx.x;
  int stride = gridDim.x * blockDim.x;
  for (int i = idx; i < NX + NW; i += stride) {
    const bool isx = i < NX;
    const int j = isx ? i : i - NX;
    float4 v = isx ? reinterpret_cast<const float4*>(x)[j]
                   : reinterpret_cast<const float4*>(w)[j];
    ushort4 o;
    o.x = f2bf_rne(v.x);
    o.y = f2bf_rne(v.y);
    o.z = f2bf_rne(v.z);
    o.w = f2bf_rne(v.w);
    if (isx)
      reinterpret_cast<ushort4*>(xbf)[j] = o;
    else
      reinterpret_cast<ushort4*>(wbf)[j] = o;
  }
}

// ---------- async global -> LDS, 16B per lane ----------
__device__ __forceinline__ void gload_lds16(const unsigned short* g, unsigned short* l) {
  __builtin_amdgcn_global_load_lds(
      (const __attribute__((address_space(1))) unsigned int*)g,
      (__attribute__((address_space(3))) unsigned int*)l, 16, 0, 0);
}

// ---------- 256x256 8-phase GEMM + fused per-tile softmax partials ----------
// (unchanged from round 6 — at the measured structure ceiling for short-K)
__global__ __launch_bounds__(512, 2) void gemm_bt(
    const unsigned short* __restrict__ A,   // [TOKENS][IN_DIM] bf16
    const unsigned short* __restrict__ B,   // [VOCAB][IN_DIM] bf16
    unsigned short* __restrict__ CB,        // d_out as ushort; row r bf16 at 64000*r+32000
    float2* __restrict__ partials) {        // [TOKENS][NCT] (tile max, tile sumexp)
  __shared__ __align__(16) unsigned short lds[65536];  // 128 KiB

  const int tid = threadIdx.x;   // 0..511
  const int lane = tid & 63;
  const int wave = tid >> 6;     // 0..7
  const int wr = wave >> 2;      // 0..1  (M)
  const int wc = wave & 3;       // 0..3  (N)

  const int bid = blockIdx.x;
  const int lid = (bid & 7) * (GEMM_GRID / 8) + (bid >> 3);
  const int rowTile = lid & 7;
  const int colTile = lid >> 3;
  const int rowBase = rowTile * BM;
  const int colBase = colTile * BN;

  // staging geometry: half-tile = 128 rows x 64 cols = 1024 chunks of 16B
  const int r0 = tid >> 3;
  const int r1 = 64 + r0;
  const int c8 = (((tid & 7) ^ (r0 & 7)) << 3);
  const unsigned short* srcA0 = A + (size_t)(rowBase + r0) * IN_DIM + c8;
  const unsigned short* srcA1 = A + (size_t)(rowBase + r1) * IN_DIM + c8;
  const unsigned short* srcB0 = B + (size_t)(colBase + r0) * IN_DIM + c8;
  const unsigned short* srcB1 = B + (size_t)(colBase + r1) * IN_DIM + c8;
  const int ldsD0 = tid * 8;
  const int ldsD1 = (512 + tid) * 8;

  auto stageA = [&](int buf, int h, int k) {
    size_t off = (size_t)h * (128 * IN_DIM) + k;
    int dst = buf * 32768 + h * 8192;
    gload_lds16(srcA0 + off, &lds[dst + ldsD0]);
    gload_lds16(srcA1 + off, &lds[dst + ldsD1]);
  };
  auto stageB = [&](int buf, int h, int k) {
    size_t off = (size_t)h * (128 * IN_DIM) + k;
    int dst = 16384 + buf * 32768 + h * 8192;
    gload_lds16(srcB0 + off, &lds[dst + ldsD0]);
    gload_lds16(srcB1 + off, &lds[dst + ldsD1]);
  };

  const int sc0 = (((lane >> 4) ^ (lane & 7)) << 3);
  const int sc1 = (((4 + (lane >> 4)) ^ (lane & 7)) << 3);
  const int aRow = (wr * 128 + (lane & 15)) * 64;
  const int bRow = 16384 + (wc * 64 + (lane & 15)) * 64;

#define LDA(buf, m, kk) (*(const s16x8*)&lds[(buf) * 32768 + aRow + (m) * 1024 + ((kk) ? sc1 : sc0)])
#define LDB(buf, n, kk) (*(const s16x8*)&lds[(buf) * 32768 + bRow + (n) * 1024 + ((kk) ? sc1 : sc0)])

  f32x4 acc[8][4] = {};

  // ---- prologue: step0 (8) + A(1) (4) + Bh0(1) (2); vmcnt(6) retires step0
  stageA(0, 0, 0);
  stageA(0, 1, 0);
  stageB(0, 0, 0);
  stageB(0, 1, 0);
  stageA(1, 0, 64);
  stageA(1, 1, 64);
  stageB(1, 0, 64);
  asm volatile("s_waitcnt vmcnt(6)" ::: "memory");
  __builtin_amdgcn_s_barrier();

#define KSTEP(bufc, kn1, kn2)                                                       \
  {                                                                                 \
    s16x8 aL[4][2], aH[4][2], bL[2][2], bH[2][2];                                   \
    /* P0: 12 reads; stage B h1(t+1) -> buf^1 @kn1 */                               \
    _Pragma("unroll") for (int m = 0; m < 4; ++m) {                                 \
      aL[m][0] = LDA(bufc, m, 0);                                                   \
      aL[m][1] = LDA(bufc, m, 1);                                                   \
    }                                                                               \
    _Pragma("unroll") for (int n = 0; n < 2; ++n) {                                 \
      bL[n][0] = LDB(bufc, n, 0);                                                   \
      bL[n][1] = LDB(bufc, n, 1);                                                   \
    }                                                                               \
    stageB((bufc) ^ 1, 1, kn1);                                                     \
    asm volatile("s_waitcnt lgkmcnt(8)" ::: "memory");                              \
    __builtin_amdgcn_s_barrier();                                                   \
    asm volatile("s_waitcnt lgkmcnt(0)" ::: "memory");                              \
    __builtin_amdgcn_s_setprio(1);                                                  \
    _Pragma("unroll") for (int m = 0; m < 4; ++m)                                   \
        _Pragma("unroll") for (int n = 0; n < 2; ++n) {                             \
      acc[m][n] = __builtin_amdgcn_mfma_f32_16x16x32_bf16(aL[m][0], bL[n][0], acc[m][n], 0, 0, 0); \
      acc[m][n] = __builtin_amdgcn_mfma_f32_16x16x32_bf16(aL[m][1], bL[n][1], acc[m][n], 0, 0, 0); \
    }                                                                               \
    __builtin_amdgcn_s_setprio(0);                                                  \
    __builtin_amdgcn_s_barrier();                                                   \
    /* P1: 8 reads aH; no stage */                                                  \
    _Pragma("unroll") for (int m = 0; m < 4; ++m) {                                 \
      aH[m][0] = LDA(bufc, 4 + m, 0);                                               \
      aH[m][1] = LDA(bufc, 4 + m, 1);                                               \
    }                                                                               \
    __builtin_amdgcn_s_barrier();                                                   \
    asm volatile("s_waitcnt lgkmcnt(0)" ::: "memory");                              \
    __builtin_amdgcn_s_setprio(1);                                                  \
    _Pragma("unroll") for (int m = 0; m < 4; ++m)                                   \
        _Pragma("unroll") for (int n = 0; n < 2; ++n) {                             \
      acc[4 + m][n] = __builtin_amdgcn_mfma_f32_16x16x32_bf16(aH[m][0], bL[n][0], acc[4 + m][n], 0, 0, 0); \
      acc[4 + m][n] = __builtin_amdgcn_mfma_f32_16x16x32_bf16(aH[m][1], bL[n][1], acc[4 + m][n], 0, 0, 0); \
    }                                                                               \
    __builtin_amdgcn_s_setprio(0);                                                  \
    __builtin_amdgcn_s_barrier();                                                   \
    /* P2: 4 reads bH; stage A h0,h1(t+2) -> bufc @kn2 (A slots dead since P1 bar) */ \
    _Pragma("unroll") for (int n = 0; n < 2; ++n) {                                 \
      bH[n][0] = LDB(bufc, 2 + n, 0);                                               \
      bH[n][1] = LDB(bufc, 2 + n, 1);                                               \
    }                                                                               \
    stageA((bufc), 0, kn2);                                                         \
    stageA((bufc), 1, kn2);                                                         \
    __builtin_amdgcn_s_barrier();                                                   \
    asm volatile("s_waitcnt lgkmcnt(0)" ::: "memory");                              \
    __builtin_amdgcn_s_setprio(1);                                                  \
    _Pragma("unroll") for (int m = 0; m < 4; ++m)                                   \
        _Pragma("unroll") for (int n = 0; n < 2; ++n) {                             \
      acc[4 + m][2 + n] = __builtin_amdgcn_mfma_f32_16x16x32_bf16(aH[m][0], bH[n][0], acc[4 + m][2 + n], 0, 0, 0); \
      acc[4 + m][2 + n] = __builtin_amdgcn_mfma_f32_16x16x32_bf16(aH[m][1], bH[n][1], acc[4 + m][2 + n], 0, 0, 0); \
    }                                                                               \
    __builtin_amdgcn_s_setprio(0);                                                  \
    __builtin_amdgcn_s_barrier();                                                   \
    /* P3: stage B h0(t+2) -> bufc @kn2 (dead since P2 bar); reg-only MFMA; */      \
    /* counted vmcnt(6) AFTER MFMA retires B h1(t+1) -> buf^1 fully resident */     \
    stageB((bufc), 0, kn2);                                                         \
    __builtin_amdgcn_s_setprio(1);                                                  \
    _Pragma("unroll") for (int m = 0; m < 4; ++m)                                   \
        _Pragma("unroll") for (int n = 0; n < 2; ++n) {                             \
      acc[m][2 + n] = __builtin_amdgcn_mfma_f32_16x16x32_bf16(aL[m][0], bH[n][0], acc[m][2 + n], 0, 0, 0); \
      acc[m][2 + n] = __builtin_amdgcn_mfma_f32_16x16x32_bf16(aL[m][1], bH[n][1], acc[m][2 + n], 0, 0, 0); \
    }                                                                               \
    __builtin_amdgcn_s_setprio(0);                                                  \
    asm volatile("s_waitcnt vmcnt(6)" ::: "memory");                                \
    __builtin_amdgcn_s_barrier();                                                   \
  }

  for (int i = 0; i < NKSTEP / 2; ++i) {
    const int k = i * 128;
    KSTEP(0, (k + 64) & (IN_DIM - 1), (k + 128) & (IN_DIM - 1));
    KSTEP(1, (k + 128) & (IN_DIM - 1), (k + 192) & (IN_DIM - 1));
  }

  // drain wrapped prefetches before LDS reuse
  asm volatile("s_waitcnt vmcnt(0)" ::: "memory");
  __syncthreads();

  // ---- (1) per-row tile stats: wave-level 64-col (max, sumexp) ----
  float* lmax = reinterpret_cast<float*>(lds);   // [256][4]
  float* lsum = lmax + 1024;                     // [256][4]
  float* bM = lmax + 2048;                       // [256] broadcast tile max
#pragma unroll
  for (int m = 0; m < 8; ++m) {
#pragma unroll
    for (int jj = 0; jj < 4; ++jj) {
      float v0 = acc[m][0][jj], v1 = acc[m][1][jj], v2 = acc[m][2][jj], v3 = acc[m][3][jj];
      float mx = fmaxf(fmaxf(v0, v1), fmaxf(v2, v3));
#pragma unroll
      for (int off = 1; off < 16; off <<= 1) mx = fmaxf(mx, __shfl_xor(mx, off));
      float s = __expf(v0 - mx) + __expf(v1 - mx) + __expf(v2 - mx) + __expf(v3 - mx);
#pragma unroll
      for (int off = 1; off < 16; off <<= 1) s += __shfl_xor(s, off);
      if ((lane & 15) == 0) {
        int r = wr * 128 + m * 16 + ((lane >> 4) << 2) + jj;
        lmax[r * 4 + wc] = mx;
        lsum[r * 4 + wc] = s;
      }
    }
  }
  __syncthreads();
  // ---- (2) cross-wave 256-col reduce -> partials + broadcast M ----
  if (tid < 256) {
    float m0 = lmax[tid * 4 + 0], m1 = lmax[tid * 4 + 1];
    float m2 = lmax[tid * 4 + 2], m3 = lmax[tid * 4 + 3];
    float M = fmaxf(fmaxf(m0, m1), fmaxf(m2, m3));
    float S = lsum[tid * 4 + 0] * __expf(m0 - M) + lsum[tid * 4 + 1] * __expf(m1 - M) +
              lsum[tid * 4 + 2] * __expf(m2 - M) + lsum[tid * 4 + 3] * __expf(m3 - M);
    partials[(size_t)(rowBase + tid) * NCT + colTile] = make_float2(M, S);
    bM[tid] = M;
  }
  __syncthreads();

  // ---- (3) pair-local packed bf16(logit - M_tile) stores ----
  const int par = lane & 1;
  const int e = (lane & 15) & ~1;  // pair base col within 16
#pragma unroll
  for (int m = 0; m < 8; ++m) {
#pragma unroll
    for (int jj = 0; jj < 4; ++jj) {
      int rloc = wr * 128 + m * 16 + ((lane >> 4) << 2) + jj;
      float M = bM[rloc];
      unsigned int p[4];
#pragma unroll
      for (int n = 0; n < 4; ++n) {
        float v = acc[m][n][jj] - M;
        float u = __shfl_xor(v, 1);
        float lo = par ? u : v;   // col e value
        float hi = par ? v : u;   // col e+1 value
        unsigned int pk;
        asm("v_cvt_pk_bf16_f32 %0, %1, %2" : "=v"(pk) : "v"(lo), "v"(hi));
        p[n] = pk;  // pk(e, n) — identical in both lanes of the pair
      }
      unsigned int q0 = par ? p[1] : p[0];
      unsigned int q1 = par ? p[3] : p[2];
      unsigned short* base = CB + (size_t)64000 * (rowBase + rloc) + 32000 +
                             colBase + wc * 64;
      *reinterpret_cast<unsigned int*>(base + 16 * par + e) = q0;       // cols  0..31
      *reinterpret_cast<unsigned int*>(base + 32 + 16 * par + e) = q1;  // cols 32..63
    }
  }
#undef LDA
#undef LDB
#undef KSTEP
}

// ---------- apply (with fused row-stat reduction): bf16 rel-logits -> fp32 probs ----------
__global__ __launch_bounds__(256) void apply_softmax(
    float* __restrict__ Out, const float2* __restrict__ partials) {
  __shared__ __align__(16) unsigned short xrow[VOCAB];  // 64 KB -> 2 blocks/CU
  __shared__ float tileM[NCT + 3];
  __shared__ float2 red[4];
  __shared__ float2 gstat;
  const int row = blockIdx.x;
  const int tid = threadIdx.x;

  // stage bf16 rel logits (src region overlaps fp32 dst region)
  const unsigned short* src = (const unsigned short*)Out + (size_t)64000 * row + 32000;
  for (int c = tid; c < VOCAB / 8; c += 256)
    reinterpret_cast<s16x8*>(xrow)[c] = reinterpret_cast<const s16x8*>(src)[c];

  // fused per-row stat reduction over NCT=125 partials
  const float2* pr = partials + (size_t)row * NCT;
  float M = -3.4e38f, S = 0.f;
  if (tid < NCT) {
    float2 v = pr[tid];
    M = v.x;
    S = v.y;
    tileM[tid] = v.x;
  }
#pragma unroll
  for (int off = 32; off > 0; off >>= 1) {
    float M2 = __shfl_down(M, off);
    float S2 = __shfl_down(S, off);
    float Mn = fmaxf(M, M2);
    S = S * __expf(M - Mn) + S2 * __expf(M2 - Mn);
    M = Mn;
  }
  if ((tid & 63) == 0) red[tid >> 6] = make_float2(M, S);
  __syncthreads();  // covers staging + red + tileM
  if (tid == 0) {
    float Mg = red[0].x, Sg = red[0].y;
#pragma unroll
    for (int w = 1; w < 4; ++w) {
      float M2 = red[w].x, S2 = red[w].y;
      float Mn = fmaxf(Mg, M2);
      Sg = Sg * __expf(Mg - Mn) + S2 * __expf(M2 - Mn);
      Mg = Mn;
    }
    gstat = make_float2(Mg, 1.f / Sg);
  }
  __syncthreads();

  const float M0 = gstat.x, invS = gstat.y;
  float4* dst = reinterpret_cast<float4*>(Out + (size_t)row * VOCAB);
  for (int c = tid; c < VOCAB / 8; c += 256) {
    s16x8 xv = reinterpret_cast<const s16x8*>(xrow)[c];
    float base = tileM[c >> 5] - M0;  // 256-col tile group
    float4 o0, o1;
    o0.x = __expf(bf2f((unsigned short)xv[0]) + base) * invS;
    o0.y = __expf(bf2f((unsigned short)xv[1]) + base) * invS;
    o0.z = __expf(bf2f((unsigned short)xv[2]) + base) * invS;
    o0.w = __expf(bf2f((unsigned short)xv[3]) + base) * invS;
    o1.x = __expf(bf2f((unsigned short)xv[4]) + base) * invS;
    o1.y = __expf(bf2f((unsigned short)xv[5]) + base) * invS;
    o1.z = __expf(bf2f((unsigned short)xv[6]) + base) * invS;
    o1.w = __expf(bf2f((unsigned short)xv[7]) + base) * invS;
    dst[c * 2] = o0;
    dst[c * 2 + 1] = o1;
  }
}

extern "C" void kernel_launch(void* const* d_in, const int* in_sizes, int n_in,
                              void* d_out, int out_size, void* d_ws, size_t ws_size,
                              hipStream_t stream) {
  const float* x = (const float*)d_in[0];
  // d_in[1] = target (int64), unused by the reference forward
  const float* w = (const float*)d_in[2];
  float* out = (float*)d_out;

  // ws layout: xbf 8MB | wbf 131MB | partials 2.05MB (~141.2MB)
  unsigned short* xbf = (unsigned short*)d_ws;
  unsigned short* wbf = xbf + (size_t)TOKENS * IN_DIM;
  float2* partials = (float2*)(wbf + (size_t)VOCAB * IN_DIM);

  convert_all<<<2048, 256, 0, stream>>>(x, w, xbf, wbf);
  gemm_bt<<<GEMM_GRID, 512, 0, stream>>>(xbf, wbf, (unsigned short*)d_out, partials);
  apply_softmax<<<TOKENS, 256, 0, stream>>>(out, partials);
}